// Round 1
// baseline (2870.873 us; speedup 1.0000x reference)
//
#include <hip/hip_runtime.h>

namespace {
constexpr int kNU = 100000, kNI = 100000, kE = 600000;
constexpr int kFU = 96, kFI = 160, kH = 128, kOUT = 64;
constexpr float kEPS = 1e-5f;
}

// ---------- input projection + ReLU: out[n,:] = relu(x[n,:] @ W + b) ----------
// block = 128 threads = one output row; x row staged in LDS; W[k*H+t] reads are
// coalesced across t and L1/L2-resident (W is 48-80 KB total).
template <int F>
__global__ void __launch_bounds__(128)
proj_relu(const float* __restrict__ x, const float* __restrict__ W,
          const float* __restrict__ b, float* __restrict__ out) {
  __shared__ float xs[F];
  const int n = blockIdx.x;
  const int t = threadIdx.x;
  for (int k = t; k < F; k += 128) xs[k] = x[(size_t)n * F + k];
  __syncthreads();
  float s = b[t];
#pragma unroll 8
  for (int k = 0; k < F; ++k) s = fmaf(xs[k], W[k * kH + t], s);
  out[(size_t)n * kH + t] = fmaxf(s, 0.0f);
}

// ---------- zero a float4-aligned region ----------
__global__ void zero4(float4* __restrict__ p, int n4) {
  int i = blockIdx.x * blockDim.x + threadIdx.x;
  const int stride = gridDim.x * blockDim.x;
  const float4 z = {0.f, 0.f, 0.f, 0.f};
  for (; i < n4; i += stride) p[i] = z;
}

// ---------- edge scatter: acc[dst,:] += feat[src,:]; cnt[dst] += 1 ----------
// 256 threads = 2 edges x 128 cols. Gather is a coalesced 512B row read
// (feature table is 51 MB -> L3 resident); scatter is fp32 global atomics.
__global__ void __launch_bounds__(256)
scatter_h(const float* __restrict__ feat, const int* __restrict__ edges,
          float* acc, float* cnt, int do_cnt) {
  const int e = blockIdx.x * 2 + (threadIdx.x >> 7);
  const int c = threadIdx.x & 127;
  if (e >= kE) return;
  const int src = edges[e];        // row 0: src index
  const int dst = edges[kE + e];   // row 1: dst index
  atomicAdd(&acc[(size_t)dst * kH + c], feat[(size_t)src * kH + c]);
  if (do_cnt && c == 0) atomicAdd(&cnt[dst], 1.0f);
}

// ---------- block (128-thread / 2-wave) sum reduction ----------
__device__ __forceinline__ float block_sum_128(float v, float* red) {
#pragma unroll
  for (int o = 1; o < 64; o <<= 1) v += __shfl_xor(v, o, 64);
  const int t = threadIdx.x;
  __syncthreads();  // protect red against reuse from a previous call
  if ((t & 63) == 0) red[t >> 6] = v;
  __syncthreads();
  return red[0] + red[1];
}

// ---------- fused SAGE (H->H) + LayerNorm (+ReLU) ----------
// out[n,t] = LN( (acc[n,:]/max(cnt,1)) @ Wl + bl + xdst[n,:] @ Wr )[t]
// Written so out may alias acc (in-place): all reads of acc happen before the
// barrier, the write after. acc/out/xdst intentionally NOT __restrict__.
__global__ void __launch_bounds__(128)
sage_ln_h(const float* acc, const float* __restrict__ cnt, const float* xdst,
          const float* __restrict__ Wl, const float* __restrict__ bl,
          const float* __restrict__ Wr, const float* __restrict__ g,
          const float* __restrict__ b, float* out, int do_relu) {
  __shared__ float a_s[kH], d_s[kH];
  __shared__ float red[2];
  const int n = blockIdx.x;
  const int t = threadIdx.x;
  const float inv = 1.0f / fmaxf(cnt[n], 1.0f);
  a_s[t] = acc[(size_t)n * kH + t] * inv;
  d_s[t] = xdst[(size_t)n * kH + t];
  __syncthreads();
  float s = bl[t];
#pragma unroll 8
  for (int k = 0; k < kH; ++k) {
    s = fmaf(a_s[k], Wl[k * kH + t], s);
    s = fmaf(d_s[k], Wr[k * kH + t], s);
  }
  const float m = block_sum_128(s, red) * (1.0f / kH);
  const float d = s - m;
  const float var = block_sum_128(d * d, red) * (1.0f / kH);
  float o = d * rsqrtf(var + kEPS) * g[t] + b[t];
  if (do_relu) o = fmaxf(o, 0.0f);
  out[(size_t)n * kH + t] = o;
}

// ---------- fused SAGE (H->OUT=64) + LayerNorm (no ReLU), final layer ----------
// block = 64 threads = one wave = one output row; LN reductions via shuffles.
__global__ void __launch_bounds__(64)
sage_ln_out(const float* acc, const float* __restrict__ cnt, const float* xdst,
            const float* __restrict__ Wl, const float* __restrict__ bl,
            const float* __restrict__ Wr, const float* __restrict__ g,
            const float* __restrict__ b, float* out) {
  __shared__ float a_s[kH], d_s[kH];
  const int n = blockIdx.x;
  const int t = threadIdx.x;  // 0..63
  const float inv = 1.0f / fmaxf(cnt[n], 1.0f);
  a_s[t] = acc[(size_t)n * kH + t] * inv;
  a_s[t + 64] = acc[(size_t)n * kH + t + 64] * inv;
  d_s[t] = xdst[(size_t)n * kH + t];
  d_s[t + 64] = xdst[(size_t)n * kH + t + 64];
  __syncthreads();
  float s = bl[t];
#pragma unroll 8
  for (int k = 0; k < kH; ++k) {
    s = fmaf(a_s[k], Wl[k * kOUT + t], s);
    s = fmaf(d_s[k], Wr[k * kOUT + t], s);
  }
  float tot = s;
#pragma unroll
  for (int o = 1; o < 64; o <<= 1) tot += __shfl_xor(tot, o, 64);
  const float m = tot * (1.0f / kOUT);
  const float d = s - m;
  float v2 = d * d;
#pragma unroll
  for (int o = 1; o < 64; o <<= 1) v2 += __shfl_xor(v2, o, 64);
  const float var = v2 * (1.0f / kOUT);
  out[(size_t)n * kOUT + t] = d * rsqrtf(var + kEPS) * g[t] + b[t];
}

extern "C" void kernel_launch(void* const* d_in, const int* in_sizes, int n_in,
                              void* d_out, int out_size, void* d_ws, size_t ws_size,
                              hipStream_t stream) {
  (void)in_sizes; (void)n_in; (void)out_size; (void)ws_size;
  const float* x_u    = (const float*)d_in[0];
  const float* x_i    = (const float*)d_in[1];
  const int*   e_ui   = (const int*)d_in[2];
  const int*   e_iu   = (const int*)d_in[3];
  const float* Wp_u   = (const float*)d_in[4];
  const float* bp_u   = (const float*)d_in[5];
  const float* Wp_i   = (const float*)d_in[6];
  const float* bp_i   = (const float*)d_in[7];
  const float* Wl0_ui = (const float*)d_in[8];
  const float* bl0_ui = (const float*)d_in[9];
  const float* Wr0_ui = (const float*)d_in[10];
  const float* Wl0_iu = (const float*)d_in[11];
  const float* bl0_iu = (const float*)d_in[12];
  const float* Wr0_iu = (const float*)d_in[13];
  const float* g0_u   = (const float*)d_in[14];
  const float* b0_u   = (const float*)d_in[15];
  const float* g0_i   = (const float*)d_in[16];
  const float* b0_i   = (const float*)d_in[17];
  const float* Wl1_ui = (const float*)d_in[18];
  const float* bl1_ui = (const float*)d_in[19];
  const float* Wr1_ui = (const float*)d_in[20];
  const float* Wl1_iu = (const float*)d_in[21];
  const float* bl1_iu = (const float*)d_in[22];
  const float* Wr1_iu = (const float*)d_in[23];
  const float* g1_u   = (const float*)d_in[24];
  const float* b1_u   = (const float*)d_in[25];
  const float* g1_i   = (const float*)d_in[26];
  const float* b1_i   = (const float*)d_in[27];

  float* ws = (float*)d_ws;
  const size_t NH = (size_t)kNU * kH;  // 12.8M floats
  float* bufA  = ws;           // h_u,  later layer-1 item accumulator
  float* bufB  = ws + NH;      // h_i,  later layer-1 user accumulator
  float* bufC  = ws + 2 * NH;  // layer-0 user accumulator -> h_u1 (in-place)
  float* bufD  = ws + 3 * NH;  // layer-0 item accumulator -> h_i1 (in-place)
  float* cnt_u = ws + 4 * NH;
  float* cnt_i = cnt_u + kNU;

  float* out_u = (float*)d_out;                 // h_u2: [100000, 64]
  float* out_i = out_u + (size_t)kNU * kOUT;    // h_i2: [100000, 64]

  const dim3 b64(64), b128(128), b256(256);

  // per-type input projection + ReLU
  proj_relu<kFU><<<kNU, b128, 0, stream>>>(x_u, Wp_u, bp_u, bufA);
  proj_relu<kFI><<<kNI, b128, 0, stream>>>(x_i, Wp_i, bp_i, bufB);

  // zero layer-0 accumulators + counts (contiguous: bufC, bufD, cnt_u, cnt_i)
  zero4<<<2048, b256, 0, stream>>>((float4*)bufC, (int)((2 * NH + 2 * kNU) / 4));

  // layer-0 scatter-mean numerators + counts
  scatter_h<<<kE / 2, b256, 0, stream>>>(bufA, e_ui, bufD, cnt_i, 1);  // users -> items
  scatter_h<<<kE / 2, b256, 0, stream>>>(bufB, e_iu, bufC, cnt_u, 1);  // items -> users

  // layer-0 SAGE + LN + ReLU (in-place over accumulators)
  sage_ln_h<<<kNI, b128, 0, stream>>>(bufD, cnt_i, bufB, Wl0_ui, bl0_ui, Wr0_ui,
                                      g0_i, b0_i, bufD, 1);            // h_i1
  sage_ln_h<<<kNU, b128, 0, stream>>>(bufC, cnt_u, bufA, Wl0_iu, bl0_iu, Wr0_iu,
                                      g0_u, b0_u, bufC, 1);            // h_u1

  // zero layer-1 accumulators (reuse bufA, bufB)
  zero4<<<2048, b256, 0, stream>>>((float4*)bufA, (int)((2 * NH) / 4));

  // layer-1 scatter-mean numerators (counts unchanged: same edge lists)
  scatter_h<<<kE / 2, b256, 0, stream>>>(bufC, e_ui, bufA, nullptr, 0); // h_u1 -> items
  scatter_h<<<kE / 2, b256, 0, stream>>>(bufD, e_iu, bufB, nullptr, 0); // h_i1 -> users

  // layer-1 SAGE + LN -> outputs
  sage_ln_out<<<kNI, b64, 0, stream>>>(bufA, cnt_i, bufD, Wl1_ui, bl1_ui, Wr1_ui,
                                       g1_i, b1_i, out_i);             // h_i2
  sage_ln_out<<<kNU, b64, 0, stream>>>(bufB, cnt_u, bufC, Wl1_iu, bl1_iu, Wr1_iu,
                                       g1_u, b1_u, out_u);             // h_u2
}

// Round 6
// 1016.301 us; speedup vs baseline: 2.8248x; 2.8248x over previous
//
#include <hip/hip_runtime.h>

typedef __attribute__((ext_vector_type(8))) __bf16 bf16x8;
typedef __attribute__((ext_vector_type(4))) float floatx4;
typedef __attribute__((ext_vector_type(8))) unsigned short ushort8v;
typedef __attribute__((ext_vector_type(4))) unsigned short ushort4v;

namespace {
constexpr int kNU = 100000, kNI = 100000, kE = 600000;
constexpr int kFU = 96, kFI = 160, kH = 128, kOUT = 64;
constexpr float kEPS = 1e-5f;
constexpr int kM = 32;       // rows per block in MFMA kernels
constexpr int kNCHUNK = 98;  // ceil(100000 / 1024)
}

__device__ __forceinline__ unsigned short f2b(float f) {  // fp32 -> bf16 RNE
  unsigned u = __builtin_bit_cast(unsigned, f);
  u += 0x7FFFu + ((u >> 16) & 1u);
  return (unsigned short)(u >> 16);
}
__device__ __forceinline__ float b2f(unsigned short h) {
  return __builtin_bit_cast(float, (unsigned)h << 16);
}
// 3-way bf16 split: v = h + m + l, residual <= ~2^-27 |v|
__device__ __forceinline__ void split3(float v, unsigned short& h,
                                       unsigned short& m, unsigned short& l) {
  h = f2b(v);
  const float r1 = v - b2f(h);   // exact
  m = f2b(r1);
  const float r2 = r1 - b2f(m);  // exact
  l = f2b(r2);
}
__device__ __forceinline__ bf16x8 ldb8(const unsigned short* p) {
  return __builtin_bit_cast(bf16x8, *(const ushort8v*)p);
}
__device__ __forceinline__ floatx4 mfma16(bf16x8 a, bf16x8 b, floatx4 c) {
  return __builtin_amdgcn_mfma_f32_16x16x32_bf16(a, b, c, 0, 0, 0);
}

// --- weight convert+transpose+3-split: Wh/Wm/Wl[n][k] = split(W[k][n]) ------
struct WcvtArgs {
  const float* src[10];
  unsigned short* dh[10];
  unsigned short* dm[10];
  unsigned short* dl[10];
  int K[10], N[10];
};
__global__ __launch_bounds__(256) void wcvt(WcvtArgs a) {
  const int m = blockIdx.y;
  const int K = a.K[m], N = a.N[m];
  const int idx = blockIdx.x * 256 + threadIdx.x;
  if (idx < K * N) {
    const int n = idx / K, k = idx - n * K;
    unsigned short h, mm, l;
    split3(a.src[m][(size_t)k * N + n], h, mm, l);
    a.dh[m][idx] = h;
    a.dm[m][idx] = mm;
    a.dl[m][idx] = l;
  }
}

// ---------------- CSR build -------------------------------------------------
__global__ void zero_int(int* __restrict__ p, int n) {
  int i = blockIdx.x * blockDim.x + threadIdx.x;
  const int st = gridDim.x * blockDim.x;
  for (; i < n; i += st) p[i] = 0;
}

__global__ __launch_bounds__(256) void hist2(const int* __restrict__ eui,
                                             const int* __restrict__ eiu,
                                             int* cnt_i, int* cnt_u) {
  const int e = blockIdx.x * 256 + threadIdx.x;
  if (e < kE) {
    atomicAdd(&cnt_i[eui[kE + e]], 1);  // dst items
    atomicAdd(&cnt_u[eiu[kE + e]], 1);  // dst users
  }
}

// exclusive scan within 1024-chunk; chunk totals to tot[dir*128 + chunk]
__global__ __launch_bounds__(1024) void scanA(const int* __restrict__ cnt_u,
                                              const int* __restrict__ cnt_i,
                                              int* ptr_u, int* ptr_i, int* tot) {
  __shared__ int sh[1024];
  const int dir = blockIdx.y;
  const int* cnt = dir ? cnt_i : cnt_u;
  int* ptr = dir ? ptr_i : ptr_u;
  const int t = threadIdx.x;
  const int i = blockIdx.x * 1024 + t;
  const int v = (i < kNU) ? cnt[i] : 0;
  sh[t] = v;
  __syncthreads();
  for (int o = 1; o < 1024; o <<= 1) {
    const int y = (t >= o) ? sh[t - o] : 0;
    __syncthreads();
    sh[t] += y;
    __syncthreads();
  }
  if (i < kNU) ptr[i] = sh[t] - v;  // exclusive within chunk
  if (t == 1023) tot[dir * 128 + blockIdx.x] = sh[1023];
}

// exclusive scan of the (<=98) chunk totals; one block per direction
__global__ __launch_bounds__(128) void scanB(int* tot) {
  __shared__ int sh[128];
  int* tp = tot + blockIdx.x * 128;
  const int t = threadIdx.x;
  const int v = (t < kNCHUNK) ? tp[t] : 0;
  sh[t] = v;
  __syncthreads();
  for (int o = 1; o < 128; o <<= 1) {
    const int y = (t >= o) ? sh[t - o] : 0;
    __syncthreads();
    sh[t] += y;
    __syncthreads();
  }
  if (t < kNCHUNK) tp[t] = sh[t] - v;  // exclusive
}

__global__ __launch_bounds__(1024) void scanC(int* ptr_u, int* ptr_i,
                                              const int* __restrict__ tot,
                                              int* cur_u, int* cur_i) {
  const int dir = blockIdx.y;
  int* ptr = dir ? ptr_i : ptr_u;
  int* cur = dir ? cur_i : cur_u;
  const int i = blockIdx.x * 1024 + threadIdx.x;
  if (i < kNU) {
    const int v = ptr[i] + tot[dir * 128 + blockIdx.x];
    ptr[i] = v;
    cur[i] = v;
  }
}

// after fill: cur[dst] == ptr[dst] + degree  (used as `end` by agg_mean)
__global__ __launch_bounds__(256) void fill2(const int* __restrict__ eui,
                                             const int* __restrict__ eiu,
                                             int* cur_i, int* cur_u,
                                             int* __restrict__ col_ui,
                                             int* __restrict__ col_iu) {
  const int e = blockIdx.x * 256 + threadIdx.x;
  if (e < kE) {
    const int p = atomicAdd(&cur_i[eui[kE + e]], 1);
    col_ui[p] = eui[e];
    const int p2 = atomicAdd(&cur_u[eiu[kE + e]], 1);
    col_iu[p2] = eiu[e];
  }
}

// ------------- gather-mean (fp32): one wave per destination row -------------
__global__ __launch_bounds__(256) void agg_mean(
    const float* __restrict__ feat, const int* __restrict__ ptr,
    const int* __restrict__ cur, const int* __restrict__ col,
    float* __restrict__ outagg, int nrows) {
  const int w = threadIdx.x >> 6, lane = threadIdx.x & 63;
  const int row = blockIdx.x * 4 + w;
  if (row >= nrows) return;
  const int beg = ptr[row], end = cur[row];
  float a0 = 0.f, a1 = 0.f;
  for (int e = beg; e < end; ++e) {
    const int src = col[e];
    const float2 v = *(const float2*)&feat[(size_t)src * kH + lane * 2];
    a0 += v.x;
    a1 += v.y;
  }
  const float inv = 1.0f / fmaxf((float)(end - beg), 1.0f);
  float2 o;
  o.x = a0 * inv;
  o.y = a1 * inv;
  *(float2*)&outagg[(size_t)row * kH + lane * 2] = o;
}

// ------- projection: relu(x @ Wp + b) -> fp32, via 3-split bf16 MFMA --------
// Split accumulators: acc (h*h, full scale) + accL (low-order terms).
template <int F>
__global__ __launch_bounds__(256) void proj_mfma(
    const float* __restrict__ x, const unsigned short* __restrict__ Wh,
    const unsigned short* __restrict__ Wm, const unsigned short* __restrict__ Wl,
    const float* __restrict__ bias, float* __restrict__ out) {
  constexpr int AS = F + 8, KC = F / 32;
  __shared__ __align__(16) unsigned short Ah[kM][AS], Am[kM][AS], Al[kM][AS];
  const int tid = threadIdx.x;
  const size_t row0 = (size_t)blockIdx.x * kM;
  for (int c = tid; c < kM * (F / 4); c += 256) {
    const int r = c / (F / 4), j = c % (F / 4);
    const float4 v = *(const float4*)&x[(row0 + r) * F + j * 4];
    const float* vv = &v.x;
    ushort4v h4, m4, l4;
#pragma unroll
    for (int u = 0; u < 4; ++u) {
      unsigned short th, tm, tl;
      split3(vv[u], th, tm, tl);
      h4[u] = th; m4[u] = tm; l4[u] = tl;
    }
    *(ushort4v*)&Ah[r][j * 4] = h4;
    *(ushort4v*)&Am[r][j * 4] = m4;
    *(ushort4v*)&Al[r][j * 4] = l4;
  }
  const int lane = tid & 63, w = tid >> 6, q = lane >> 4, ln = lane & 15;
  floatx4 acc[2][2] = {}, accL[2][2] = {};
  __syncthreads();
#pragma unroll
  for (int kc = 0; kc < KC; ++kc) {
    bf16x8 bh[2], bm[2], bl_[2];
#pragma unroll
    for (int t = 0; t < 2; ++t) {
      const int off = (w * 32 + t * 16 + ln) * F + kc * 32 + q * 8;
      bh[t] = ldb8(&Wh[off]);
      bm[t] = ldb8(&Wm[off]);
      bl_[t] = ldb8(&Wl[off]);
    }
#pragma unroll
    for (int mt = 0; mt < 2; ++mt) {
      const int ro = mt * 16 + ln, co = kc * 32 + q * 8;
      const bf16x8 ah = ldb8(&Ah[ro][co]);
      const bf16x8 am = ldb8(&Am[ro][co]);
      const bf16x8 al = ldb8(&Al[ro][co]);
#pragma unroll
      for (int t = 0; t < 2; ++t) {
        acc[mt][t] = mfma16(ah, bh[t], acc[mt][t]);  // full scale
        floatx4 cl = accL[mt][t];                    // low-order (~2^-9)
        cl = mfma16(ah, bm[t], cl);
        cl = mfma16(am, bh[t], cl);
        cl = mfma16(ah, bl_[t], cl);
        cl = mfma16(al, bh[t], cl);
        cl = mfma16(am, bm[t], cl);
        accL[mt][t] = cl;
      }
    }
  }
#pragma unroll
  for (int t = 0; t < 2; ++t) {
    const int col = w * 32 + t * 16 + ln;
    const float bv = bias[col];
#pragma unroll
    for (int mt = 0; mt < 2; ++mt)
#pragma unroll
      for (int r = 0; r < 4; ++r)
        out[(row0 + mt * 16 + q * 4 + r) * kH + col] =
            fmaxf((acc[mt][t][r] + accL[mt][t][r]) + bv, 0.f);
  }
}

// --- fused SAGE + bias + LN (+ReLU) via 3-split bf16 MFMA, fp32 I/O ---------
// D = A1 @ WL^T + A2 @ WR^T + bl ; then row LayerNorm(g,b) [+ReLU].
// Split accumulators as in proj_mfma. Two-pass LN (centered variance).
// Safe for out to alias A2 (same row block): A2 reads complete before writes.
template <int NOUT, bool RELU>
__global__ __launch_bounds__(NOUT * 2) void sage_mfma(
    const float* A1,   // mean-agg fp32 [rows][128]
    const float* A2,   // x_dst fp32 [rows][128]
    const unsigned short* __restrict__ WLh, const unsigned short* __restrict__ WLm,
    const unsigned short* __restrict__ WLl, const unsigned short* __restrict__ WRh,
    const unsigned short* __restrict__ WRm, const unsigned short* __restrict__ WRl,
    const float* __restrict__ bl, const float* __restrict__ gg,
    const float* __restrict__ bb, float* out) {
  constexpr int K = 128, AS = K + 8, NTHR = NOUT * 2;
  __shared__ __align__(16) unsigned short Ab[6][kM][AS];  // A1{h,m,l} A2{h,m,l}
  float* Cs = (float*)&Ab[0][0][0];  // reused post-MFMA: [kM][NOUT+1] fp32
  const int tid = threadIdx.x;
  const size_t row0 = (size_t)blockIdx.x * kM;

  for (int c = tid; c < 2 * kM * (K / 4); c += NTHR) {  // 2048 float4 chunks
    const int mat = c >> 10, cc = c & 1023, r = cc >> 5, j = cc & 31;
    const float4 v = *(const float4*)((mat ? A2 : A1) + (row0 + r) * K + j * 4);
    const float* vv = &v.x;
    ushort4v h4, m4, l4;
#pragma unroll
    for (int u = 0; u < 4; ++u) {
      unsigned short th, tm, tl;
      split3(vv[u], th, tm, tl);
      h4[u] = th; m4[u] = tm; l4[u] = tl;
    }
    *(ushort4v*)&Ab[mat * 3 + 0][r][j * 4] = h4;
    *(ushort4v*)&Ab[mat * 3 + 1][r][j * 4] = m4;
    *(ushort4v*)&Ab[mat * 3 + 2][r][j * 4] = l4;
  }

  const int lane = tid & 63, w = tid >> 6, q = lane >> 4, ln = lane & 15;
  floatx4 acc[2][2] = {}, accL[2][2] = {};
  __syncthreads();
#pragma unroll
  for (int kc = 0; kc < 4; ++kc) {
    bf16x8 BL[3][2], BR[3][2];
#pragma unroll
    for (int t = 0; t < 2; ++t) {
      const int off = (w * 32 + t * 16 + ln) * K + kc * 32 + q * 8;
      BL[0][t] = ldb8(&WLh[off]);
      BL[1][t] = ldb8(&WLm[off]);
      BL[2][t] = ldb8(&WLl[off]);
      BR[0][t] = ldb8(&WRh[off]);
      BR[1][t] = ldb8(&WRm[off]);
      BR[2][t] = ldb8(&WRl[off]);
    }
#pragma unroll
    for (int mt = 0; mt < 2; ++mt) {
      const int ro = mt * 16 + ln, co = kc * 32 + q * 8;
      const bf16x8 a1h = ldb8(&Ab[0][ro][co]);
      const bf16x8 a1m = ldb8(&Ab[1][ro][co]);
      const bf16x8 a1l = ldb8(&Ab[2][ro][co]);
      const bf16x8 a2h = ldb8(&Ab[3][ro][co]);
      const bf16x8 a2m = ldb8(&Ab[4][ro][co]);
      const bf16x8 a2l = ldb8(&Ab[5][ro][co]);
#pragma unroll
      for (int t = 0; t < 2; ++t) {
        floatx4 c = acc[mt][t];                 // full-scale h*h terms
        c = mfma16(a1h, BL[0][t], c);
        c = mfma16(a2h, BR[0][t], c);
        acc[mt][t] = c;
        floatx4 cl = accL[mt][t];               // low-order terms (~2^-9)
        cl = mfma16(a1h, BL[1][t], cl);
        cl = mfma16(a1m, BL[0][t], cl);
        cl = mfma16(a1h, BL[2][t], cl);
        cl = mfma16(a1l, BL[0][t], cl);
        cl = mfma16(a1m, BL[1][t], cl);
        cl = mfma16(a2h, BR[1][t], cl);
        cl = mfma16(a2m, BR[0][t], cl);
        cl = mfma16(a2h, BR[2][t], cl);
        cl = mfma16(a2l, BR[0][t], cl);
        cl = mfma16(a2m, BR[1][t], cl);
        accL[mt][t] = cl;
      }
    }
  }
  __syncthreads();  // done reading Ab; safe to overwrite with Cs
#pragma unroll
  for (int t = 0; t < 2; ++t) {
    const int col = w * 32 + t * 16 + ln;
    const float bv = bl[col];
#pragma unroll
    for (int mt = 0; mt < 2; ++mt)
#pragma unroll
      for (int r = 0; r < 4; ++r)
        Cs[(mt * 16 + q * 4 + r) * (NOUT + 1) + col] =
            (acc[mt][t][r] + accL[mt][t][r]) + bv;
  }
  __syncthreads();
  // Two-pass LayerNorm: NOUT/16 threads per row, 16 cols each
  constexpr int TPR = NOUT / 16;
  const int r = tid / TPR, sub = tid % TPR;
  float vals[16], s = 0.f;
#pragma unroll
  for (int j = 0; j < 16; ++j) {
    const float v = Cs[r * (NOUT + 1) + sub * 16 + j];
    vals[j] = v;
    s += v;
  }
#pragma unroll
  for (int o = 1; o < TPR; o <<= 1) s += __shfl_xor(s, o, 64);
  const float mean = s * (1.0f / NOUT);
  float s2 = 0.f;
#pragma unroll
  for (int j = 0; j < 16; ++j) {
    const float d = vals[j] - mean;
    s2 += d * d;
  }
#pragma unroll
  for (int o = 1; o < TPR; o <<= 1) s2 += __shfl_xor(s2, o, 64);
  const float rstd = rsqrtf(s2 * (1.0f / NOUT) + kEPS);
  float* op = out + (row0 + r) * NOUT + sub * 16;
#pragma unroll
  for (int j = 0; j < 16; j += 4) {
    float4 o4;
    float* oo = &o4.x;
#pragma unroll
    for (int jj = 0; jj < 4; ++jj) {
      float o = (vals[j + jj] - mean) * rstd * gg[sub * 16 + j + jj] +
                bb[sub * 16 + j + jj];
      if (RELU) o = fmaxf(o, 0.f);
      oo[jj] = o;
    }
    *(float4*)&op[j] = o4;
  }
}

extern "C" void kernel_launch(void* const* d_in, const int* in_sizes, int n_in,
                              void* d_out, int out_size, void* d_ws, size_t ws_size,
                              hipStream_t stream) {
  (void)in_sizes; (void)n_in; (void)out_size; (void)ws_size;
  const float* x_u    = (const float*)d_in[0];
  const float* x_i    = (const float*)d_in[1];
  const int*   e_ui   = (const int*)d_in[2];
  const int*   e_iu   = (const int*)d_in[3];
  const float* Wp_u   = (const float*)d_in[4];
  const float* bp_u   = (const float*)d_in[5];
  const float* Wp_i   = (const float*)d_in[6];
  const float* bp_i   = (const float*)d_in[7];
  const float* Wl0_ui = (const float*)d_in[8];
  const float* bl0_ui = (const float*)d_in[9];
  const float* Wr0_ui = (const float*)d_in[10];
  const float* Wl0_iu = (const float*)d_in[11];
  const float* bl0_iu = (const float*)d_in[12];
  const float* Wr0_iu = (const float*)d_in[13];
  const float* g0_u   = (const float*)d_in[14];
  const float* b0_u   = (const float*)d_in[15];
  const float* g0_i   = (const float*)d_in[16];
  const float* b0_i   = (const float*)d_in[17];
  const float* Wl1_ui = (const float*)d_in[18];
  const float* bl1_ui = (const float*)d_in[19];
  const float* Wr1_ui = (const float*)d_in[20];
  const float* Wl1_iu = (const float*)d_in[21];
  const float* bl1_iu = (const float*)d_in[22];
  const float* Wr1_iu = (const float*)d_in[23];
  const float* g1_u   = (const float*)d_in[24];
  const float* b1_u   = (const float*)d_in[25];
  const float* g1_i   = (const float*)d_in[26];
  const float* b1_i   = (const float*)d_in[27];

  // ---- workspace: 4 fp32 tables (205 MB) + 3-split weights + CSR (~8 MB) --
  float* pf = (float*)d_ws;
  const size_t NH = (size_t)kNU * kH;  // 12.8M
  float* hu   = pf;          // h_u0 -> h_u1 (in-place)
  float* hi   = pf + NH;     // h_i0 -> h_i1
  float* aggI = pf + 2 * NH;
  float* aggU = pf + 3 * NH;
  unsigned short* wh = (unsigned short*)(pf + 4 * NH);  // 131072 ushorts each
  unsigned short* wm = wh + 131072;
  unsigned short* wl = wm + 131072;
  int* pi = (int*)(wl + 131072);
  int* cnt_u = pi; pi += kNU;
  int* cnt_i = pi; pi += kNU;
  int* ptr_u = pi; pi += kNU;
  int* ptr_i = pi; pi += kNU;
  int* cur_u = pi; pi += kNU;
  int* cur_i = pi; pi += kNU;
  int* tot   = pi; pi += 2 * 128;
  int* col_ui = pi; pi += kE;
  int* col_iu = pi; pi += kE;

  // weight sub-offsets (identical layout in h/m/l sets)
  const int oPu = 0, oPi = 12288, o0Lui = 32768, o0Rui = 49152,
            o0Liu = 65536, o0Riu = 81920, o1Lui = 98304, o1Rui = 106496,
            o1Liu = 114688, o1Riu = 122880;

  float* out_u = (float*)d_out;               // h_u2: [100000][64]
  float* out_i = out_u + (size_t)kNU * kOUT;  // h_i2: [100000][64]

  // ---- weight convert/transpose/3-split ----
  WcvtArgs wa;
  const float* wsrc[10] = {Wp_u, Wp_i, Wl0_ui, Wr0_ui, Wl0_iu, Wr0_iu,
                           Wl1_ui, Wr1_ui, Wl1_iu, Wr1_iu};
  const int woff[10] = {oPu, oPi, o0Lui, o0Rui, o0Liu, o0Riu,
                        o1Lui, o1Rui, o1Liu, o1Riu};
  const int wK[10] = {kFU, kFI, kH, kH, kH, kH, kH, kH, kH, kH};
  const int wN[10] = {kH, kH, kH, kH, kH, kH, kOUT, kOUT, kOUT, kOUT};
  for (int i = 0; i < 10; ++i) {
    wa.src[i] = wsrc[i];
    wa.dh[i] = wh + woff[i];
    wa.dm[i] = wm + woff[i];
    wa.dl[i] = wl + woff[i];
    wa.K[i] = wK[i];
    wa.N[i] = wN[i];
  }
  wcvt<<<dim3(80, 10), 256, 0, stream>>>(wa);

  // ---- CSR build (both directions) ----
  zero_int<<<256, 256, 0, stream>>>(cnt_u, 2 * kNU);  // cnt_u, cnt_i contiguous
  hist2<<<(kE + 255) / 256, 256, 0, stream>>>(e_ui, e_iu, cnt_i, cnt_u);
  scanA<<<dim3(kNCHUNK, 2), 1024, 0, stream>>>(cnt_u, cnt_i, ptr_u, ptr_i, tot);
  scanB<<<2, 128, 0, stream>>>(tot);
  scanC<<<dim3(kNCHUNK, 2), 1024, 0, stream>>>(ptr_u, ptr_i, tot, cur_u, cur_i);
  fill2<<<(kE + 255) / 256, 256, 0, stream>>>(e_ui, e_iu, cur_i, cur_u, col_ui, col_iu);

  // ---- projections (fp32 out) ----
  proj_mfma<kFU><<<kNU / kM, 256, 0, stream>>>(x_u, wh + oPu, wm + oPu,
                                               wl + oPu, bp_u, hu);
  proj_mfma<kFI><<<kNI / kM, 256, 0, stream>>>(x_i, wh + oPi, wm + oPi,
                                               wl + oPi, bp_i, hi);

  // ---- layer 0 ----
  agg_mean<<<kNI / 4, 256, 0, stream>>>(hu, ptr_i, cur_i, col_ui, aggI, kNI);
  agg_mean<<<kNU / 4, 256, 0, stream>>>(hi, ptr_u, cur_u, col_iu, aggU, kNU);
  sage_mfma<kH, true><<<kNI / kM, 256, 0, stream>>>(
      aggI, hi, wh + o0Lui, wm + o0Lui, wl + o0Lui,
      wh + o0Rui, wm + o0Rui, wl + o0Rui, bl0_ui, g0_i, b0_i, hi);  // h_i1
  sage_mfma<kH, true><<<kNU / kM, 256, 0, stream>>>(
      aggU, hu, wh + o0Liu, wm + o0Liu, wl + o0Liu,
      wh + o0Riu, wm + o0Riu, wl + o0Riu, bl0_iu, g0_u, b0_u, hu);  // h_u1

  // ---- layer 1 ----
  agg_mean<<<kNI / 4, 256, 0, stream>>>(hu, ptr_i, cur_i, col_ui, aggI, kNI);
  agg_mean<<<kNU / 4, 256, 0, stream>>>(hi, ptr_u, cur_u, col_iu, aggU, kNU);
  sage_mfma<kOUT, false><<<kNI / kM, 128, 0, stream>>>(
      aggI, hi, wh + o1Lui, wm + o1Lui, wl + o1Lui,
      wh + o1Rui, wm + o1Rui, wl + o1Rui, bl1_ui, g1_i, b1_i, out_i);  // h_i2
  sage_mfma<kOUT, false><<<kNU / kM, 128, 0, stream>>>(
      aggU, hu, wh + o1Liu, wm + o1Liu, wl + o1Liu,
      wh + o1Riu, wm + o1Riu, wl + o1Riu, bl1_iu, g1_u, b1_u, out_u);  // h_u2
}